// Round 4
// baseline (418.552 us; speedup 1.0000x reference)
//
#include <hip/hip_runtime.h>
#include <cstdint>
#include <cstddef>

typedef unsigned short u16;
typedef __attribute__((ext_vector_type(8))) __bf16 bf16x8;
typedef __attribute__((ext_vector_type(4))) float f32x4;
typedef __attribute__((ext_vector_type(8))) u16 u16x8;
typedef __attribute__((ext_vector_type(4))) u16 u16x4;

#define MTOT   38400   // B*T*N rows
#define DMODEL 256
#define NQKV   768
#define NN     400
#define NBT    96      // B*T
#define SCALE  0.17677669529663687f   // 1/sqrt(32), folded into Wq/bq at prep

__device__ __forceinline__ u16 f2b(float f){
  __bf16 b = (__bf16)f;
  return __builtin_bit_cast(u16, b);
}

__device__ __forceinline__ void g2l16(const void* g, void* l){
  __builtin_amdgcn_global_load_lds(
      (const __attribute__((address_space(1))) unsigned int*)g,
      (__attribute__((address_space(3))) unsigned int*)l,
      16, 0, 0);
}

// ---------------- prep: cast x -> bf16 ----------------
__global__ __launch_bounds__(256) void cast_x_kernel(const float* __restrict__ x,
                                                     u16* __restrict__ xb, int n8){
  int i = blockIdx.x * 256 + threadIdx.x;
  if (i >= n8) return;
  const f32x4* xp = (const f32x4*)x;
  f32x4 a = xp[2*i], b = xp[2*i+1];
  u16x8 o;
  o[0]=f2b(a[0]); o[1]=f2b(a[1]); o[2]=f2b(a[2]); o[3]=f2b(a[3]);
  o[4]=f2b(b[0]); o[5]=f2b(b[1]); o[6]=f2b(b[2]); o[7]=f2b(b[3]);
  ((u16x8*)xb)[i] = o;
}

// ---------------- prep: pack Wq*S/Wk/Wv -> bf16 [768][256], bias -> f32[768] ----------------
__global__ __launch_bounds__(256) void prep_w_kernel(
    const float* __restrict__ wq, const float* __restrict__ wk, const float* __restrict__ wv,
    const float* __restrict__ bq, const float* __restrict__ bk, const float* __restrict__ bv,
    u16* __restrict__ wqkv, float* __restrict__ bqkv){
  int i = blockIdx.x * 256 + threadIdx.x;      // 49152 threads, 4 elems each
  int g = i >> 14;                              // 16384 float4 per matrix
  int rem = (i & 16383) * 4;
  const float* w = (g == 0) ? wq : ((g == 1) ? wk : wv);
  float sc = (g == 0) ? SCALE : 1.0f;           // fold 1/sqrt(hd) into Q projection
  f32x4 v = *(const f32x4*)(w + rem);
  u16x4 o; o[0]=f2b(v[0]*sc); o[1]=f2b(v[1]*sc); o[2]=f2b(v[2]*sc); o[3]=f2b(v[3]*sc);
  *(u16x4*)(wqkv + (size_t)i*4) = o;
  if (i < NQKV) bqkv[i] = (i < 256) ? bq[i]*SCALE : ((i < 512) ? bk[i-256] : bv[i-512]);
}

// ---------------- QKV GEMM, 2-phase pipelined ----------------
__global__ __launch_bounds__(256,2) void gemm_qkv_kernel(
    const u16* __restrict__ xb, const u16* __restrict__ wqkv,
    const float* __restrict__ bqkv, u16* __restrict__ qkv){
  __shared__ u16 a_lds[2][128*64];
  __shared__ u16 b_lds[2][128*64];
  const int tid = threadIdx.x, lane = tid & 63, wave = tid >> 6;
  const int bn = blockIdx.x % 6, bm = blockIdx.x / 6;
  const int m0 = bm*128, n0 = bn*128;
  const int wm = (wave>>1)*64, wn = (wave&1)*64;
  const int lr = lane & 15, lk = lane >> 4;
  f32x4 acc[4][4] = {};

  // per-wave staging of one k-step (8 x 16B global_load_lds, pre-swizzled source)
  auto stage = [&](int buf, int k0){
    #pragma unroll
    for (int i = 0; i < 4; ++i){
      int off  = (wave*4 + i)*1024 + lane*16;   // byte offset in 16KB tile
      int row  = off >> 7;                      // /128B per row (64 bf16)
      int colb = off & 127;
      int scolb = colb ^ ((row & 7) << 4);      // inverse-swizzled SOURCE (rule #21)
      g2l16(xb   + (size_t)(m0+row)*256 + k0 + (scolb>>1), (char*)a_lds[buf] + (wave*4+i)*1024);
      g2l16(wqkv + (size_t)(n0+row)*256 + k0 + (scolb>>1), (char*)b_lds[buf] + (wave*4+i)*1024);
    }
  };

  stage(0, 0);
  #pragma unroll
  for (int ks = 0; ks < 4; ++ks){
    if (ks < 3){
      stage((ks+1)&1, (ks+1)*64);
      asm volatile("s_waitcnt vmcnt(8)" ::: "memory");   // own prev-step loads done; next 8 in flight
    } else {
      asm volatile("s_waitcnt vmcnt(0)" ::: "memory");
    }
    __builtin_amdgcn_s_barrier();
    const char* al = (const char*)a_lds[ks&1];
    const char* bl = (const char*)b_lds[ks&1];
    #pragma unroll
    for (int sub = 0; sub < 2; ++sub){
      bf16x8 af[4], bfr[4];
      #pragma unroll
      for (int i = 0; i < 4; ++i){
        int ra = wm + i*16 + lr;
        af[i]  = *(const bf16x8*)(al + ra*128 + ((sub*64 + lk*16) ^ ((ra&7)<<4)));
        int rb = wn + i*16 + lr;
        bfr[i] = *(const bf16x8*)(bl + rb*128 + ((sub*64 + lk*16) ^ ((rb&7)<<4)));
      }
      #pragma unroll
      for (int i = 0; i < 4; ++i)
        #pragma unroll
        for (int j = 0; j < 4; ++j)
          acc[i][j] = __builtin_amdgcn_mfma_f32_16x16x32_bf16(af[i], bfr[j], acc[i][j], 0, 0, 0);
    }
    __builtin_amdgcn_s_barrier();
  }
  #pragma unroll
  for (int j = 0; j < 4; ++j){
    int n = n0 + wn + j*16 + lr;               // D col = lane&15
    float bias = bqkv[n];
    #pragma unroll
    for (int i = 0; i < 4; ++i){
      int mb = m0 + wm + i*16 + lk*4;          // D row = (lane>>4)*4 + r
      #pragma unroll
      for (int r = 0; r < 4; ++r)
        qkv[(size_t)(mb + r)*NQKV + n] = f2b(acc[i][j][r] + bias);
    }
  }
}

// ---------------- V^T to global: vtg[bt*8+h][d 0..31][416], k-cols 400..415 zeroed ----------------
__global__ __launch_bounds__(256) void vt_prep_kernel(const u16* __restrict__ qkv,
                                                      u16* __restrict__ vtg){
  const int bh = blockIdx.x, bt = bh >> 3, h = bh & 7;
  const u16* vsrc = qkv + (size_t)bt*NN*NQKV + 512 + h*32;
  u16* dst = vtg + (size_t)bh*32*416;
  for (int idx = threadIdx.x; idx < 32*52; idx += 256){
    int d = idx / 52, j = idx % 52;
    int k0 = j*8;
    u16x8 o;
    if (k0 < 400){
      #pragma unroll
      for (int e = 0; e < 8; ++e) o[e] = vsrc[(size_t)(k0+e)*NQKV + d];
    } else {
      #pragma unroll
      for (int e = 0; e < 8; ++e) o[e] = 0;
    }
    *(u16x8*)(dst + d*416 + k0) = o;
  }
}

// ---------------- attention: per (b,t,h) block, swapped-QK layout ----------------
// LDS: K [400][32] bf16 XOR-swizzled (25600 B)
//      P [4 waves][2 bufs][16][40] bf16 (10240 B)       total 35840 B -> 3+ blocks/CU
#define PW_STRIDE 40
#define K_BYTES   25600

__global__ __launch_bounds__(256,3) void attn_kernel(
    const u16* __restrict__ qkv, const u16* __restrict__ vtg,
    const float* __restrict__ adj, float* __restrict__ hout){
  __shared__ __align__(16) char smem[35840];
  u16* p_all = (u16*)(smem + K_BYTES);
  const int tid = threadIdx.x, lane = tid & 63, wave = tid >> 6;
  const int h = blockIdx.x / NBT, bt = blockIdx.x % NBT;   // bid%8 == bt%8 -> same-bt heads share an XCD
  const int lq = lane & 15, lk = lane >> 4;
  const u16* qkvbt = qkv + (size_t)bt*NN*NQKV + h*32;
  const u16* vth   = vtg + (size_t)(bt*8 + h)*32*416;

  // ---- stage K [400][32] via global_load_lds (16B), pre-swizzled source, linear LDS dest
  {
    const u16* kbase = qkvbt + 256;
    int rsub = lane >> 2;                 // 0..15
    int colb = (lane & 3) * 16;           // 0,16,32,48 bytes
    for (int c = wave; c < 25; c += 4){
      int row  = c*16 + rsub;
      int scol = colb ^ ((row & 3) << 4); // inverse swizzle on SOURCE
      g2l16(kbase + (size_t)row*NQKV + (scol >> 1), smem + c*1024);
    }
  }
  __syncthreads();

  const float* adjbt = adj + (size_t)bt*NN*NN;
  u16* pw = p_all + wave*(2*16*PW_STRIDE);
  const f32x4 z = {0.f, 0.f, 0.f, 0.f};

  for (int t25 = wave; t25 < 25; t25 += 4){
    const int q0 = t25*16;
    // Q B-frag from global: B[row=lane&15 = q][k=(lane>>4)*8+e]
    bf16x8 qf = *(const bf16x8*)(qkvbt + (size_t)(q0 + lq)*NQKV + lk*8);
    // QK^T swapped: s[kt] holds S[q = lq][k = kt*16 + lk*4 + r]
    f32x4 s[25];
    #pragma unroll
    for (int kt = 0; kt < 25; ++kt){
      int row = kt*16 + lq;
      bf16x8 kf = *(const bf16x8*)((const char*)smem + row*64 + ((lk*16) ^ ((row & 3) << 4)));
      s[kt] = __builtin_amdgcn_mfma_f32_16x16x32_bf16(kf, qf, z, 0, 0, 0);
    }
    // adj mask: contiguous f32x4 per lane (coalesced)
    const float* arow = adjbt + (size_t)(q0 + lq)*NN + lk*4;
    #pragma unroll
    for (int kt = 0; kt < 25; ++kt){
      f32x4 a = *(const f32x4*)(arow + kt*16);
      s[kt] *= a;
    }
    // row max (lane-local tree + 2 shuffles across lk groups)
    f32x4 mv = s[0];
    #pragma unroll
    for (int kt = 1; kt < 25; ++kt){
      mv[0]=fmaxf(mv[0],s[kt][0]); mv[1]=fmaxf(mv[1],s[kt][1]);
      mv[2]=fmaxf(mv[2],s[kt][2]); mv[3]=fmaxf(mv[3],s[kt][3]);
    }
    float m = fmaxf(fmaxf(mv[0],mv[1]), fmaxf(mv[2],mv[3]));
    m = fmaxf(m, __shfl_xor(m, 16)); m = fmaxf(m, __shfl_xor(m, 32));
    // exp + sum (4 independent chains)
    f32x4 sv = z;
    #pragma unroll
    for (int kt = 0; kt < 25; ++kt){
      #pragma unroll
      for (int j = 0; j < 4; ++j){
        float e = __expf(s[kt][j] - m);
        s[kt][j] = e; sv[j] += e;
      }
    }
    float sum = (sv[0]+sv[1]) + (sv[2]+sv[3]);
    sum += __shfl_xor(sum, 16); sum += __shfl_xor(sum, 32);
    float inv = 1.0f / sum;
    // PV over 13 windows of 32 k; P through tiny per-wave LDS; V^T frags from global (L1/L2)
    f32x4 o0 = z, o1 = z;
    #pragma unroll
    for (int w = 0; w < 13; ++w){
      u16* buf = pw + (w & 1)*(16*PW_STRIDE);
      u16x4 pk0, pk1;
      #pragma unroll
      for (int j = 0; j < 4; ++j) pk0[j] = f2b(s[2*w][j]);
      if (w < 12){
        #pragma unroll
        for (int j = 0; j < 4; ++j) pk1[j] = f2b(s[2*w+1][j]);
      } else {
        pk1[0]=0; pk1[1]=0; pk1[2]=0; pk1[3]=0;
      }
      *(u16x4*)(buf + lq*PW_STRIDE + lk*4)      = pk0;
      *(u16x4*)(buf + lq*PW_STRIDE + 16 + lk*4) = pk1;
      bf16x8 pf = *(const bf16x8*)((const char*)buf + lq*80 + lk*16);
      bf16x8 v0 = *(const bf16x8*)(vth + (size_t)lq*416      + w*32 + lk*8);
      bf16x8 v1 = *(const bf16x8*)(vth + (size_t)(16+lq)*416 + w*32 + lk*8);
      o0 = __builtin_amdgcn_mfma_f32_16x16x32_bf16(pf, v0, o0, 0, 0, 0);
      o1 = __builtin_amdgcn_mfma_f32_16x16x32_bf16(pf, v1, o1, 0, 0, 0);
    }
    // epilogue: O[q = lk*4+r][d = lq (+16)], scale by 1/sum of that q-row
    float* orow = hout + (size_t)(bt*NN + q0)*DMODEL + h*32;
    #pragma unroll
    for (int r = 0; r < 4; ++r){
      float invq = __shfl(inv, lk*4 + r);
      orow[(lk*4 + r)*DMODEL + lq]      = o0[r]*invq;
      orow[(lk*4 + r)*DMODEL + 16 + lq] = o1[r]*invq;
    }
  }
}

// ---------------- residual + LayerNorm ----------------
__global__ __launch_bounds__(256) void resid_ln_kernel(
    const float* __restrict__ hbuf, const float* __restrict__ x,
    const float* __restrict__ gamma, const float* __restrict__ beta,
    float* __restrict__ out){
  const int wave = threadIdx.x >> 6, lane = threadIdx.x & 63;
  const int row = blockIdx.x*4 + wave;
  const f32x4* hp = (const f32x4*)(hbuf + (size_t)row*DMODEL);
  const f32x4* xp = (const f32x4*)(x    + (size_t)row*DMODEL);
  f32x4 y = hp[lane] + xp[lane];
  float s = y[0] + y[1] + y[2] + y[3];
  s += __shfl_xor(s, 1);  s += __shfl_xor(s, 2);  s += __shfl_xor(s, 4);
  s += __shfl_xor(s, 8);  s += __shfl_xor(s, 16); s += __shfl_xor(s, 32);
  float mu = s * (1.0f/256.0f);
  f32x4 d = y - mu;
  float vs = d[0]*d[0] + d[1]*d[1] + d[2]*d[2] + d[3]*d[3];
  vs += __shfl_xor(vs, 1);  vs += __shfl_xor(vs, 2);  vs += __shfl_xor(vs, 4);
  vs += __shfl_xor(vs, 8);  vs += __shfl_xor(vs, 16); vs += __shfl_xor(vs, 32);
  float rs = rsqrtf(vs * (1.0f/256.0f) + 1e-5f);
  f32x4 g = ((const f32x4*)gamma)[lane];
  f32x4 b = ((const f32x4*)beta)[lane];
  f32x4 o = d*rs*g + b;
  ((f32x4*)(out + (size_t)row*DMODEL))[lane] = o;
}

// ---------------- launch ----------------
extern "C" void kernel_launch(void* const* d_in, const int* in_sizes, int n_in,
                              void* d_out, int out_size, void* d_ws, size_t ws_size,
                              hipStream_t stream){
  const float* x     = (const float*)d_in[0];
  const float* adj   = (const float*)d_in[1];
  const float* Wq    = (const float*)d_in[2];
  const float* bq    = (const float*)d_in[3];
  const float* Wk    = (const float*)d_in[4];
  const float* bk    = (const float*)d_in[5];
  const float* Wv    = (const float*)d_in[6];
  const float* bv    = (const float*)d_in[7];
  const float* gamma = (const float*)d_in[8];
  const float* beta  = (const float*)d_in[9];
  float* out = (float*)d_out;
  char* ws = (char*)d_ws;

  // workspace carve (bytes) — xb overlays hbuf (dead by the time attn writes hbuf)
  u16*   vtg  = (u16*)  (ws + 0);            // 768*32*416*2  = 20,447,232
  u16*   wqkv = (u16*)  (ws + 20447232);     // 768*256*2     = 393,216
  float* bqkv = (float*)(ws + 20840448);     // 768*4         = 3,072
  u16*   qkv  = (u16*)  (ws + 20843520);     // 38400*768*2   = 58,982,400
  float* hbuf = (float*)(ws + 79825920);     // 38400*256*4   = 39,321,600 -> ends 119,147,520
  u16*   xb   = (u16*)  (ws + 79825920);     // 19,660,800 (overlay on hbuf; dead after gemm)

  cast_x_kernel<<<4800, 256, 0, stream>>>(x, xb, 9830400/8);
  prep_w_kernel<<<192, 256, 0, stream>>>(Wq, Wk, Wv, bq, bk, bv, wqkv, bqkv);
  gemm_qkv_kernel<<<1800, 256, 0, stream>>>(xb, wqkv, bqkv, qkv);
  vt_prep_kernel<<<768, 256, 0, stream>>>(qkv, vtg);
  attn_kernel<<<768, 256, 0, stream>>>(qkv, vtg, adj, hbuf);
  resid_ln_kernel<<<9600, 256, 0, stream>>>(hbuf, x, gamma, beta, out);
}

// Round 5
// 350.965 us; speedup vs baseline: 1.1926x; 1.1926x over previous
//
#include <hip/hip_runtime.h>
#include <cstdint>
#include <cstddef>

typedef unsigned short u16;
typedef __attribute__((ext_vector_type(8))) __bf16 bf16x8;
typedef __attribute__((ext_vector_type(4))) float f32x4;
typedef __attribute__((ext_vector_type(8))) u16 u16x8;
typedef __attribute__((ext_vector_type(4))) u16 u16x4;

#define MTOT   38400   // B*T*N rows
#define DMODEL 256
#define NQKV   768
#define NN     400
#define NBT    96      // B*T
#define SCALE  0.17677669529663687f   // 1/sqrt(32), folded into Wq/bq at prep

__device__ __forceinline__ u16 f2b(float f){
  __bf16 b = (__bf16)f;
  return __builtin_bit_cast(u16, b);
}

__device__ __forceinline__ void g2l16(const void* g, void* l){
  __builtin_amdgcn_global_load_lds(
      (const __attribute__((address_space(1))) unsigned int*)g,
      (__attribute__((address_space(3))) unsigned int*)l,
      16, 0, 0);
}

// ---------------- prep: cast x -> bf16 ----------------
__global__ __launch_bounds__(256) void cast_x_kernel(const float* __restrict__ x,
                                                     u16* __restrict__ xb, int n8){
  int i = blockIdx.x * 256 + threadIdx.x;
  if (i >= n8) return;
  const f32x4* xp = (const f32x4*)x;
  f32x4 a = xp[2*i], b = xp[2*i+1];
  u16x8 o;
  o[0]=f2b(a[0]); o[1]=f2b(a[1]); o[2]=f2b(a[2]); o[3]=f2b(a[3]);
  o[4]=f2b(b[0]); o[5]=f2b(b[1]); o[6]=f2b(b[2]); o[7]=f2b(b[3]);
  ((u16x8*)xb)[i] = o;
}

// ---------------- prep: pack Wq*S/Wk/Wv -> bf16 [768][256], bias -> f32[768] ----------------
__global__ __launch_bounds__(256) void prep_w_kernel(
    const float* __restrict__ wq, const float* __restrict__ wk, const float* __restrict__ wv,
    const float* __restrict__ bq, const float* __restrict__ bk, const float* __restrict__ bv,
    u16* __restrict__ wqkv, float* __restrict__ bqkv){
  int i = blockIdx.x * 256 + threadIdx.x;      // 49152 threads, 4 elems each
  int g = i >> 14;                              // 16384 float4 per matrix
  int rem = (i & 16383) * 4;
  const float* w = (g == 0) ? wq : ((g == 1) ? wk : wv);
  float sc = (g == 0) ? SCALE : 1.0f;           // fold 1/sqrt(hd) into Q projection
  f32x4 v = *(const f32x4*)(w + rem);
  u16x4 o; o[0]=f2b(v[0]*sc); o[1]=f2b(v[1]*sc); o[2]=f2b(v[2]*sc); o[3]=f2b(v[3]*sc);
  *(u16x4*)(wqkv + (size_t)i*4) = o;
  if (i < NQKV) bqkv[i] = (i < 256) ? bq[i]*SCALE : ((i < 512) ? bk[i-256] : bv[i-512]);
}

// ---------------- QKV GEMM, 2-phase pipelined (counted vmcnt) ----------------
__global__ __launch_bounds__(256,2) void gemm_qkv_kernel(
    const u16* __restrict__ xb, const u16* __restrict__ wqkv,
    const float* __restrict__ bqkv, u16* __restrict__ qkv){
  __shared__ u16 a_lds[2][128*64];
  __shared__ u16 b_lds[2][128*64];
  const int tid = threadIdx.x, lane = tid & 63, wave = tid >> 6;
  const int bn = blockIdx.x % 6, bm = blockIdx.x / 6;
  const int m0 = bm*128, n0 = bn*128;
  const int wm = (wave>>1)*64, wn = (wave&1)*64;
  const int lr = lane & 15, lk = lane >> 4;
  f32x4 acc[4][4] = {};

  auto stage = [&](int buf, int k0){
    #pragma unroll
    for (int i = 0; i < 4; ++i){
      int off  = (wave*4 + i)*1024 + lane*16;   // byte offset in 16KB tile
      int row  = off >> 7;                      // /128B per row (64 bf16)
      int colb = off & 127;
      int scolb = colb ^ ((row & 7) << 4);      // inverse-swizzled SOURCE (rule #21)
      g2l16(xb   + (size_t)(m0+row)*256 + k0 + (scolb>>1), (char*)a_lds[buf] + (wave*4+i)*1024);
      g2l16(wqkv + (size_t)(n0+row)*256 + k0 + (scolb>>1), (char*)b_lds[buf] + (wave*4+i)*1024);
    }
  };

  stage(0, 0);
  #pragma unroll
  for (int ks = 0; ks < 4; ++ks){
    if (ks < 3){
      stage((ks+1)&1, (ks+1)*64);
      asm volatile("s_waitcnt vmcnt(8)" ::: "memory");   // own prev-step loads done; next 8 in flight
    } else {
      asm volatile("s_waitcnt vmcnt(0)" ::: "memory");
    }
    __builtin_amdgcn_s_barrier();
    const char* al = (const char*)a_lds[ks&1];
    const char* bl = (const char*)b_lds[ks&1];
    #pragma unroll
    for (int sub = 0; sub < 2; ++sub){
      bf16x8 af[4], bfr[4];
      #pragma unroll
      for (int i = 0; i < 4; ++i){
        int ra = wm + i*16 + lr;
        af[i]  = *(const bf16x8*)(al + ra*128 + ((sub*64 + lk*16) ^ ((ra&7)<<4)));
        int rb = wn + i*16 + lr;
        bfr[i] = *(const bf16x8*)(bl + rb*128 + ((sub*64 + lk*16) ^ ((rb&7)<<4)));
      }
      #pragma unroll
      for (int i = 0; i < 4; ++i)
        #pragma unroll
        for (int j = 0; j < 4; ++j)
          acc[i][j] = __builtin_amdgcn_mfma_f32_16x16x32_bf16(af[i], bfr[j], acc[i][j], 0, 0, 0);
    }
    __builtin_amdgcn_s_barrier();
  }
  #pragma unroll
  for (int j = 0; j < 4; ++j){
    int n = n0 + wn + j*16 + lr;               // D col = lane&15
    float bias = bqkv[n];
    #pragma unroll
    for (int i = 0; i < 4; ++i){
      int mb = m0 + wm + i*16 + lk*4;          // D row = (lane>>4)*4 + r
      #pragma unroll
      for (int r = 0; r < 4; ++r)
        qkv[(size_t)(mb + r)*NQKV + n] = f2b(acc[i][j][r] + bias);
    }
  }
}

// ---------------- attention: per (b,t,h) block, 8 waves, swapped-QK layout ----------------
// LDS: K  [400][32] bf16 XOR-swizzled, 25600 B
//      vT [32][448] bf16, stride 896B (7x128B -> uniform row bank phase),
//         XOR-swizzled byte ^= (d&7)<<4, k-cols 400..447 zeroed, 28672 B
//      P  [8 waves][2 bufs][16][40] bf16, 20480 B
// total 74752 B -> 2 blocks/CU = 16 waves/CU; VGPR must be <=128 (launch_bounds 512,4)
#define PW_STRIDE 40
#define K_BYTES   25600
#define VT_BYTES  28672
#define ATTN_LDS  (K_BYTES + VT_BYTES + 20480)

__global__ __launch_bounds__(512,4) void attn_kernel(
    const u16* __restrict__ qkv, const float* __restrict__ adj, float* __restrict__ hout){
  extern __shared__ __align__(16) char smem[];
  u16* vT    = (u16*)(smem + K_BYTES);
  u16* p_all = (u16*)(smem + K_BYTES + VT_BYTES);
  const int tid = threadIdx.x, lane = tid & 63, wave = tid >> 6;
  const int h = blockIdx.x / NBT, bt = blockIdx.x % NBT;   // bid%8 == bt%8 -> same-bt heads share an XCD
  const int lq = lane & 15, lk = lane >> 4;
  const u16* qkvbt = qkv + (size_t)bt*NN*NQKV + h*32;

  // ---- stage K [400][32] via global_load_lds (16B), pre-swizzled source, linear LDS dest
  {
    const u16* kbase = qkvbt + 256;
    int rsub = lane >> 2;                 // 0..15
    int colb = (lane & 3) * 16;           // 0,16,32,48 bytes
    for (int c = wave; c < 25; c += 8){
      int row  = c*16 + rsub;
      int scol = colb ^ ((row & 3) << 4); // inverse swizzle on SOURCE
      g2l16(kbase + (size_t)row*NQKV + (scol >> 1), smem + c*1024);
    }
  }
  // ---- stage V transposed + swizzled: value (d,k) at byte d*896 + ((2k) ^ ((d&7)<<4))
  for (int c = tid; c < 1600; c += 512){
    int row = c >> 2, cc = (c & 3)*8;     // row = k index, cc = d base
    u16x8 v = *(const u16x8*)(qkvbt + 512 + (size_t)row*NQKV + cc);
    #pragma unroll
    for (int e = 0; e < 8; ++e){
      int d = cc + e;
      *(u16*)((char*)vT + d*896 + ((row*2) ^ ((d&7)<<4))) = v[e];
    }
  }
  // zero pad k-cols 400..447 (w=12 swizzled reads touch up to k=447)
  for (int i = tid; i < 32*48; i += 512){
    int d = i / 48, k = 400 + (i % 48);
    *(u16*)((char*)vT + d*896 + ((k*2) ^ ((d&7)<<4))) = 0;
  }
  __syncthreads();

  const float* adjbt = adj + (size_t)bt*NN*NN;
  u16* pw = p_all + wave*(2*16*PW_STRIDE);
  const f32x4 z = {0.f, 0.f, 0.f, 0.f};

  for (int t25 = wave; t25 < 25; t25 += 8){
    const int q0 = t25*16;
    // Q B-frag from global: B[row=lane&15 = q][k=(lane>>4)*8+e]
    bf16x8 qf = *(const bf16x8*)(qkvbt + (size_t)(q0 + lq)*NQKV + lk*8);
    // QK^T swapped: s[kt] holds S[q = lq][k = kt*16 + lk*4 + r]
    f32x4 s[25];
    __builtin_amdgcn_s_setprio(1);
    #pragma unroll
    for (int kt = 0; kt < 25; ++kt){
      int row = kt*16 + lq;
      bf16x8 kf = *(const bf16x8*)((const char*)smem + row*64 + ((lk*16) ^ ((row & 3) << 4)));
      s[kt] = __builtin_amdgcn_mfma_f32_16x16x32_bf16(kf, qf, z, 0, 0, 0);
    }
    __builtin_amdgcn_s_setprio(0);
    // adj mask: contiguous f32x4 per lane (coalesced)
    const float* arow = adjbt + (size_t)(q0 + lq)*NN + lk*4;
    #pragma unroll
    for (int kt = 0; kt < 25; ++kt){
      f32x4 a = *(const f32x4*)(arow + kt*16);
      s[kt] *= a;
    }
    // row max (lane-local tree + 2 shuffles across lk groups)
    f32x4 mv = s[0];
    #pragma unroll
    for (int kt = 1; kt < 25; ++kt){
      mv[0]=fmaxf(mv[0],s[kt][0]); mv[1]=fmaxf(mv[1],s[kt][1]);
      mv[2]=fmaxf(mv[2],s[kt][2]); mv[3]=fmaxf(mv[3],s[kt][3]);
    }
    float m = fmaxf(fmaxf(mv[0],mv[1]), fmaxf(mv[2],mv[3]));
    m = fmaxf(m, __shfl_xor(m, 16)); m = fmaxf(m, __shfl_xor(m, 32));
    // exp + sum (4 independent chains)
    f32x4 sv = z;
    #pragma unroll
    for (int kt = 0; kt < 25; ++kt){
      #pragma unroll
      for (int j = 0; j < 4; ++j){
        float e = __expf(s[kt][j] - m);
        s[kt][j] = e; sv[j] += e;
      }
    }
    float sum = (sv[0]+sv[1]) + (sv[2]+sv[3]);
    sum += __shfl_xor(sum, 16); sum += __shfl_xor(sum, 32);
    float inv = 1.0f / sum;
    // PV over 13 windows of 32 k; P through tiny per-wave LDS (conflict-free swizzled vT reads)
    f32x4 o0 = z, o1 = z;
    #pragma unroll
    for (int w = 0; w < 13; ++w){
      u16* buf = pw + (w & 1)*(16*PW_STRIDE);
      u16x4 pk0, pk1;
      #pragma unroll
      for (int j = 0; j < 4; ++j) pk0[j] = f2b(s[2*w][j]);
      if (w < 12){
        #pragma unroll
        for (int j = 0; j < 4; ++j) pk1[j] = f2b(s[2*w+1][j]);
      } else {
        pk1[0]=0; pk1[1]=0; pk1[2]=0; pk1[3]=0;
      }
      *(u16x4*)(buf + lq*PW_STRIDE + lk*4)      = pk0;
      *(u16x4*)(buf + lq*PW_STRIDE + 16 + lk*4) = pk1;
      bf16x8 pf = *(const bf16x8*)((const char*)buf + lq*80 + lk*16);
      int cb = (w*64 + lk*16) ^ ((lq & 7) << 4);
      bf16x8 v0 = *(const bf16x8*)((const char*)vT + lq*896      + cb);
      bf16x8 v1 = *(const bf16x8*)((const char*)vT + (16+lq)*896 + cb);
      o0 = __builtin_amdgcn_mfma_f32_16x16x32_bf16(pf, v0, o0, 0, 0, 0);
      o1 = __builtin_amdgcn_mfma_f32_16x16x32_bf16(pf, v1, o1, 0, 0, 0);
    }
    // epilogue: O[q = lk*4+r][d = lq (+16)], scale by 1/sum of that q-row
    float* orow = hout + (size_t)(bt*NN + q0)*DMODEL + h*32;
    #pragma unroll
    for (int r = 0; r < 4; ++r){
      float invq = __shfl(inv, lk*4 + r);
      orow[(lk*4 + r)*DMODEL + lq]      = o0[r]*invq;
      orow[(lk*4 + r)*DMODEL + 16 + lq] = o1[r]*invq;
    }
  }
}

// ---------------- residual + LayerNorm ----------------
__global__ __launch_bounds__(256) void resid_ln_kernel(
    const float* __restrict__ hbuf, const float* __restrict__ x,
    const float* __restrict__ gamma, const float* __restrict__ beta,
    float* __restrict__ out){
  const int wave = threadIdx.x >> 6, lane = threadIdx.x & 63;
  const int row = blockIdx.x*4 + wave;
  const f32x4* hp = (const f32x4*)(hbuf + (size_t)row*DMODEL);
  const f32x4* xp = (const f32x4*)(x    + (size_t)row*DMODEL);
  f32x4 y = hp[lane] + xp[lane];
  float s = y[0] + y[1] + y[2] + y[3];
  s += __shfl_xor(s, 1);  s += __shfl_xor(s, 2);  s += __shfl_xor(s, 4);
  s += __shfl_xor(s, 8);  s += __shfl_xor(s, 16); s += __shfl_xor(s, 32);
  float mu = s * (1.0f/256.0f);
  f32x4 d = y - mu;
  float vs = d[0]*d[0] + d[1]*d[1] + d[2]*d[2] + d[3]*d[3];
  vs += __shfl_xor(vs, 1);  vs += __shfl_xor(vs, 2);  vs += __shfl_xor(vs, 4);
  vs += __shfl_xor(vs, 8);  vs += __shfl_xor(vs, 16); vs += __shfl_xor(vs, 32);
  float rs = rsqrtf(vs * (1.0f/256.0f) + 1e-5f);
  f32x4 g = ((const f32x4*)gamma)[lane];
  f32x4 b = ((const f32x4*)beta)[lane];
  f32x4 o = d*rs*g + b;
  ((f32x4*)(out + (size_t)row*DMODEL))[lane] = o;
}

// ---------------- launch ----------------
extern "C" void kernel_launch(void* const* d_in, const int* in_sizes, int n_in,
                              void* d_out, int out_size, void* d_ws, size_t ws_size,
                              hipStream_t stream){
  const float* x     = (const float*)d_in[0];
  const float* adj   = (const float*)d_in[1];
  const float* Wq    = (const float*)d_in[2];
  const float* bq    = (const float*)d_in[3];
  const float* Wk    = (const float*)d_in[4];
  const float* bk    = (const float*)d_in[5];
  const float* Wv    = (const float*)d_in[6];
  const float* bv    = (const float*)d_in[7];
  const float* gamma = (const float*)d_in[8];
  const float* beta  = (const float*)d_in[9];
  float* out = (float*)d_out;
  char* ws = (char*)d_ws;

  // workspace carve (bytes)
  u16*   xb   = (u16*)  (ws + 0);            // 38400*256*2   = 19,660,800
  u16*   wqkv = (u16*)  (ws + 19660800);     // 768*256*2     = 393,216
  float* bqkv = (float*)(ws + 20054016);     // 768*4         = 3,072
  u16*   qkv  = (u16*)  (ws + 20057088);     // 38400*768*2   = 58,982,400
  float* hbuf = (float*)(ws + 79039488);     // 38400*256*4   = 39,321,600  -> ends 118,361,088

  cast_x_kernel<<<4800, 256, 0, stream>>>(x, xb, 9830400/8);
  prep_w_kernel<<<192, 256, 0, stream>>>(Wq, Wk, Wv, bq, bk, bv, wqkv, bqkv);
  gemm_qkv_kernel<<<1800, 256, 0, stream>>>(xb, wqkv, bqkv, qkv);
  (void)hipFuncSetAttribute((const void*)attn_kernel,
                            hipFuncAttributeMaxDynamicSharedMemorySize, ATTN_LDS);
  attn_kernel<<<768, 512, ATTN_LDS, stream>>>(qkv, adj, hbuf);
  resid_ln_kernel<<<9600, 256, 0, stream>>>(hbuf, x, gamma, beta, out);
}

// Round 6
// 257.874 us; speedup vs baseline: 1.6231x; 1.3610x over previous
//
#include <hip/hip_runtime.h>
#include <cstdint>
#include <cstddef>

typedef unsigned short u16;
typedef __attribute__((ext_vector_type(8))) __bf16 bf16x8;
typedef __attribute__((ext_vector_type(4))) float f32x4;
typedef __attribute__((ext_vector_type(8))) u16 u16x8;
typedef __attribute__((ext_vector_type(4))) u16 u16x4;

#define MTOT   38400   // B*T*N rows
#define DMODEL 256
#define NQKV   768
#define NN     400
#define NBT    96      // B*T
#define SCALE  0.17677669529663687f   // 1/sqrt(32), folded into Wq/bq at prep

__device__ __forceinline__ u16 f2b(float f){
  __bf16 b = (__bf16)f;
  return __builtin_bit_cast(u16, b);
}

__device__ __forceinline__ void g2l16(const void* g, void* l){
  __builtin_amdgcn_global_load_lds(
      (const __attribute__((address_space(1))) unsigned int*)g,
      (__attribute__((address_space(3))) unsigned int*)l,
      16, 0, 0);
}

// ---------------- prep: cast x -> bf16 ----------------
__global__ __launch_bounds__(256) void cast_x_kernel(const float* __restrict__ x,
                                                     u16* __restrict__ xb, int n8){
  int i = blockIdx.x * 256 + threadIdx.x;
  if (i >= n8) return;
  const f32x4* xp = (const f32x4*)x;
  f32x4 a = xp[2*i], b = xp[2*i+1];
  u16x8 o;
  o[0]=f2b(a[0]); o[1]=f2b(a[1]); o[2]=f2b(a[2]); o[3]=f2b(a[3]);
  o[4]=f2b(b[0]); o[5]=f2b(b[1]); o[6]=f2b(b[2]); o[7]=f2b(b[3]);
  ((u16x8*)xb)[i] = o;
}

// ---------------- prep: pack Wq*S/Wk/Wv -> bf16 [768][256], bias -> f32[768] ----------------
__global__ __launch_bounds__(256) void prep_w_kernel(
    const float* __restrict__ wq, const float* __restrict__ wk, const float* __restrict__ wv,
    const float* __restrict__ bq, const float* __restrict__ bk, const float* __restrict__ bv,
    u16* __restrict__ wqkv, float* __restrict__ bqkv){
  int i = blockIdx.x * 256 + threadIdx.x;      // 49152 threads, 4 elems each
  int g = i >> 14;                              // 16384 float4 per matrix
  int rem = (i & 16383) * 4;
  const float* w = (g == 0) ? wq : ((g == 1) ? wk : wv);
  float sc = (g == 0) ? SCALE : 1.0f;           // fold 1/sqrt(hd) into Q projection
  f32x4 v = *(const f32x4*)(w + rem);
  u16x4 o; o[0]=f2b(v[0]*sc); o[1]=f2b(v[1]*sc); o[2]=f2b(v[2]*sc); o[3]=f2b(v[3]*sc);
  *(u16x4*)(wqkv + (size_t)i*4) = o;
  if (i < NQKV) bqkv[i] = (i < 256) ? bq[i]*SCALE : ((i < 512) ? bk[i-256] : bv[i-512]);
}

// ---------------- QKV GEMM, 2-phase pipelined (counted vmcnt) ----------------
__global__ __launch_bounds__(256,2) void gemm_qkv_kernel(
    const u16* __restrict__ xb, const u16* __restrict__ wqkv,
    const float* __restrict__ bqkv, u16* __restrict__ qkv){
  __shared__ u16 a_lds[2][128*64];
  __shared__ u16 b_lds[2][128*64];
  const int tid = threadIdx.x, lane = tid & 63, wave = tid >> 6;
  const int bn = blockIdx.x % 6, bm = blockIdx.x / 6;
  const int m0 = bm*128, n0 = bn*128;
  const int wm = (wave>>1)*64, wn = (wave&1)*64;
  const int lr = lane & 15, lk = lane >> 4;
  f32x4 acc[4][4] = {};

  auto stage = [&](int buf, int k0){
    #pragma unroll
    for (int i = 0; i < 4; ++i){
      int off  = (wave*4 + i)*1024 + lane*16;   // byte offset in 16KB tile
      int row  = off >> 7;                      // /128B per row (64 bf16)
      int colb = off & 127;
      int scolb = colb ^ ((row & 7) << 4);      // inverse-swizzled SOURCE (rule #21)
      g2l16(xb   + (size_t)(m0+row)*256 + k0 + (scolb>>1), (char*)a_lds[buf] + (wave*4+i)*1024);
      g2l16(wqkv + (size_t)(n0+row)*256 + k0 + (scolb>>1), (char*)b_lds[buf] + (wave*4+i)*1024);
    }
  };

  stage(0, 0);
  #pragma unroll
  for (int ks = 0; ks < 4; ++ks){
    if (ks < 3){
      stage((ks+1)&1, (ks+1)*64);
      asm volatile("s_waitcnt vmcnt(8)" ::: "memory");   // own prev-step loads done; next 8 in flight
    } else {
      asm volatile("s_waitcnt vmcnt(0)" ::: "memory");
    }
    __builtin_amdgcn_s_barrier();
    const char* al = (const char*)a_lds[ks&1];
    const char* bl = (const char*)b_lds[ks&1];
    #pragma unroll
    for (int sub = 0; sub < 2; ++sub){
      bf16x8 af[4], bfr[4];
      #pragma unroll
      for (int i = 0; i < 4; ++i){
        int ra = wm + i*16 + lr;
        af[i]  = *(const bf16x8*)(al + ra*128 + ((sub*64 + lk*16) ^ ((ra&7)<<4)));
        int rb = wn + i*16 + lr;
        bfr[i] = *(const bf16x8*)(bl + rb*128 + ((sub*64 + lk*16) ^ ((rb&7)<<4)));
      }
      #pragma unroll
      for (int i = 0; i < 4; ++i)
        #pragma unroll
        for (int j = 0; j < 4; ++j)
          acc[i][j] = __builtin_amdgcn_mfma_f32_16x16x32_bf16(af[i], bfr[j], acc[i][j], 0, 0, 0);
    }
    __builtin_amdgcn_s_barrier();
  }
  #pragma unroll
  for (int j = 0; j < 4; ++j){
    int n = n0 + wn + j*16 + lr;               // D col = lane&15
    float bias = bqkv[n];
    #pragma unroll
    for (int i = 0; i < 4; ++i){
      int mb = m0 + wm + i*16 + lk*4;          // D row = (lane>>4)*4 + r
      #pragma unroll
      for (int r = 0; r < 4; ++r)
        qkv[(size_t)(mb + r)*NQKV + n] = f2b(acc[i][j][r] + bias);
    }
  }
}

// ---------------- attention: per (b,t,h) block, 8 waves, flash-style online softmax ----------------
// LDS: K  [400][32] bf16 XOR-swizzled, 25600 B
//      vT [32][448] bf16, stride 896B, swizzled byte ^= (d&7)<<4, k 400..447 zeroed, 28672 B
//      P  [8 waves][2 bufs][16][40] bf16, 20480 B
// total 74752 B -> 2 blocks/CU = 16 waves/CU. Online softmax keeps VGPR ~80 (no s[25] spill).
#define PW_STRIDE 40
#define K_BYTES   25600
#define VT_BYTES  28672
#define ATTN_LDS  (K_BYTES + VT_BYTES + 20480)

__global__ __launch_bounds__(512,4) void attn_kernel(
    const u16* __restrict__ qkv, const float* __restrict__ adj, float* __restrict__ hout){
  extern __shared__ __align__(16) char smem[];
  u16* vT    = (u16*)(smem + K_BYTES);
  u16* p_all = (u16*)(smem + K_BYTES + VT_BYTES);
  const int tid = threadIdx.x, lane = tid & 63, wave = tid >> 6;
  const int h = blockIdx.x / NBT, bt = blockIdx.x % NBT;   // bid%8 == bt%8 -> same-bt heads share an XCD
  const int lq = lane & 15, lk = lane >> 4;
  const u16* qkvbt = qkv + (size_t)bt*NN*NQKV + h*32;

  // ---- stage K [400][32] via global_load_lds (16B), pre-swizzled source, linear LDS dest
  {
    const u16* kbase = qkvbt + 256;
    int rsub = lane >> 2;                 // 0..15
    int colb = (lane & 3) * 16;           // 0,16,32,48 bytes
    for (int c = wave; c < 25; c += 8){
      int row  = c*16 + rsub;
      int scol = colb ^ ((row & 3) << 4); // inverse swizzle on SOURCE
      g2l16(kbase + (size_t)row*NQKV + (scol >> 1), smem + c*1024);
    }
  }
  // ---- stage V transposed + swizzled: value (d,k) at byte d*896 + ((2k) ^ ((d&7)<<4))
  for (int c = tid; c < 1600; c += 512){
    int row = c >> 2, cc = (c & 3)*8;     // row = k index, cc = d base
    u16x8 v = *(const u16x8*)(qkvbt + 512 + (size_t)row*NQKV + cc);
    #pragma unroll
    for (int e = 0; e < 8; ++e){
      int d = cc + e;
      *(u16*)((char*)vT + d*896 + ((row*2) ^ ((d&7)<<4))) = v[e];
    }
  }
  // zero pad k-cols 400..447
  for (int i = tid; i < 32*48; i += 512){
    int d = i / 48, k = 400 + (i % 48);
    *(u16*)((char*)vT + d*896 + ((k*2) ^ ((d&7)<<4))) = 0;
  }
  __syncthreads();

  const float* adjbt = adj + (size_t)bt*NN*NN;
  u16* pw = p_all + wave*(2*16*PW_STRIDE);
  const f32x4 z = {0.f, 0.f, 0.f, 0.f};

  for (int t25 = wave; t25 < 25; t25 += 8){
    const int q0 = t25*16;
    // Q B-frag from global: B[row=lane&15 = q][k=(lane>>4)*8+e]
    bf16x8 qf = *(const bf16x8*)(qkvbt + (size_t)(q0 + lq)*NQKV + lk*8);
    const float* arow = adjbt + (size_t)(q0 + lq)*NN;
    f32x4 o0 = z, o1 = z;
    float m_run = -1e30f, l_run = 0.f;
    // adj prefetch for window 0
    f32x4 a0 = *(const f32x4*)(arow + lk*4);
    f32x4 a1 = *(const f32x4*)(arow + 16 + lk*4);

    #pragma unroll
    for (int w = 0; w < 12; ++w){
      // QK^T for window w (swapped: lane holds S[q=lq][k=w*32 + lk*4+r (+16)])
      int r0 = w*32 + lq;
      int r1 = w*32 + 16 + lq;
      bf16x8 k0 = *(const bf16x8*)((const char*)smem + r0*64 + ((lk*16) ^ ((r0 & 3) << 4)));
      bf16x8 k1 = *(const bf16x8*)((const char*)smem + r1*64 + ((lk*16) ^ ((r1 & 3) << 4)));
      __builtin_amdgcn_s_setprio(1);
      f32x4 s0 = __builtin_amdgcn_mfma_f32_16x16x32_bf16(k0, qf, z, 0, 0, 0);
      f32x4 s1 = __builtin_amdgcn_mfma_f32_16x16x32_bf16(k1, qf, z, 0, 0, 0);
      __builtin_amdgcn_s_setprio(0);
      f32x4 ca0 = a0, ca1 = a1;
      if (w < 11){
        a0 = *(const f32x4*)(arow + (w+1)*32 + lk*4);
        a1 = *(const f32x4*)(arow + (w+1)*32 + 16 + lk*4);
      } else {
        a0 = *(const f32x4*)(arow + 384 + lk*4);   // tail window adj
      }
      s0 *= ca0; s1 *= ca1;
      // window max for row lq
      float wmx = fmaxf(fmaxf(fmaxf(s0[0],s0[1]), fmaxf(s0[2],s0[3])),
                        fmaxf(fmaxf(s1[0],s1[1]), fmaxf(s1[2],s1[3])));
      wmx = fmaxf(wmx, __shfl_xor(wmx, 16)); wmx = fmaxf(wmx, __shfl_xor(wmx, 32));
      // deferred-max update (T13): rescale only when some row grows past THR=8
      if (!__all(wmx <= m_run + 8.f)){
        float m_new = fmaxf(m_run, wmx);
        float sc = __expf(m_run - m_new);
        m_run = m_new;
        l_run *= sc;
        float osc0 = __shfl(sc, lk*4+0), osc1 = __shfl(sc, lk*4+1);
        float osc2 = __shfl(sc, lk*4+2), osc3 = __shfl(sc, lk*4+3);
        o0[0]*=osc0; o0[1]*=osc1; o0[2]*=osc2; o0[3]*=osc3;
        o1[0]*=osc0; o1[1]*=osc1; o1[2]*=osc2; o1[3]*=osc3;
      }
      f32x4 e0, e1;
      #pragma unroll
      for (int j = 0; j < 4; ++j){ e0[j] = __expf(s0[j] - m_run); e1[j] = __expf(s1[j] - m_run); }
      l_run += (e0[0]+e0[1]+e0[2]+e0[3]) + (e1[0]+e1[1]+e1[2]+e1[3]);
      // P -> per-wave LDS (layout fix), then PV
      u16* buf = pw + (w & 1)*(16*PW_STRIDE);
      u16x4 pk0, pk1;
      #pragma unroll
      for (int j = 0; j < 4; ++j){ pk0[j] = f2b(e0[j]); pk1[j] = f2b(e1[j]); }
      *(u16x4*)(buf + lq*PW_STRIDE + lk*4)      = pk0;
      *(u16x4*)(buf + lq*PW_STRIDE + 16 + lk*4) = pk1;
      bf16x8 pf = *(const bf16x8*)((const char*)buf + lq*80 + lk*16);
      int cb = (w*64 + lk*16) ^ ((lq & 7) << 4);
      bf16x8 v0 = *(const bf16x8*)((const char*)vT + lq*896      + cb);
      bf16x8 v1 = *(const bf16x8*)((const char*)vT + (16+lq)*896 + cb);
      o0 = __builtin_amdgcn_mfma_f32_16x16x32_bf16(pf, v0, o0, 0, 0, 0);
      o1 = __builtin_amdgcn_mfma_f32_16x16x32_bf16(pf, v1, o1, 0, 0, 0);
    }
    // ---- tail window: kt=24 (k 384..399), second half zero
    {
      int r0 = 384 + lq;
      bf16x8 k0 = *(const bf16x8*)((const char*)smem + r0*64 + ((lk*16) ^ ((r0 & 3) << 4)));
      f32x4 s0 = __builtin_amdgcn_mfma_f32_16x16x32_bf16(k0, qf, z, 0, 0, 0);
      s0 *= a0;                                  // a0 = arow[384 + lk*4..] from prefetch
      float wmx = fmaxf(fmaxf(s0[0],s0[1]), fmaxf(s0[2],s0[3]));
      wmx = fmaxf(wmx, __shfl_xor(wmx, 16)); wmx = fmaxf(wmx, __shfl_xor(wmx, 32));
      if (!__all(wmx <= m_run + 8.f)){
        float m_new = fmaxf(m_run, wmx);
        float sc = __expf(m_run - m_new);
        m_run = m_new;
        l_run *= sc;
        float osc0 = __shfl(sc, lk*4+0), osc1 = __shfl(sc, lk*4+1);
        float osc2 = __shfl(sc, lk*4+2), osc3 = __shfl(sc, lk*4+3);
        o0[0]*=osc0; o0[1]*=osc1; o0[2]*=osc2; o0[3]*=osc3;
        o1[0]*=osc0; o1[1]*=osc1; o1[2]*=osc2; o1[3]*=osc3;
      }
      f32x4 e0;
      #pragma unroll
      for (int j = 0; j < 4; ++j) e0[j] = __expf(s0[j] - m_run);
      l_run += e0[0]+e0[1]+e0[2]+e0[3];
      u16* buf = pw;                             // w=12 even; buf0 last used at w=10 (consumed)
      u16x4 pk0, pk1;
      #pragma unroll
      for (int j = 0; j < 4; ++j){ pk0[j] = f2b(e0[j]); pk1[j] = 0; }
      *(u16x4*)(buf + lq*PW_STRIDE + lk*4)      = pk0;
      *(u16x4*)(buf + lq*PW_STRIDE + 16 + lk*4) = pk1;
      bf16x8 pf = *(const bf16x8*)((const char*)buf + lq*80 + lk*16);
      int cb = (12*64 + lk*16) ^ ((lq & 7) << 4);
      bf16x8 v0 = *(const bf16x8*)((const char*)vT + lq*896      + cb);
      bf16x8 v1 = *(const bf16x8*)((const char*)vT + (16+lq)*896 + cb);
      o0 = __builtin_amdgcn_mfma_f32_16x16x32_bf16(pf, v0, o0, 0, 0, 0);
      o1 = __builtin_amdgcn_mfma_f32_16x16x32_bf16(pf, v1, o1, 0, 0, 0);
    }
    // ---- final row-sum reduce + epilogue
    float l = l_run;
    l += __shfl_xor(l, 16); l += __shfl_xor(l, 32);
    float inv = 1.0f / l;
    float* orow = hout + (size_t)(bt*NN + q0)*DMODEL + h*32;
    #pragma unroll
    for (int r = 0; r < 4; ++r){
      float invq = __shfl(inv, lk*4 + r);
      orow[(lk*4 + r)*DMODEL + lq]      = o0[r]*invq;
      orow[(lk*4 + r)*DMODEL + 16 + lq] = o1[r]*invq;
    }
  }
}

// ---------------- residual + LayerNorm ----------------
__global__ __launch_bounds__(256) void resid_ln_kernel(
    const float* __restrict__ hbuf, const float* __restrict__ x,
    const float* __restrict__ gamma, const float* __restrict__ beta,
    float* __restrict__ out){
  const int wave = threadIdx.x >> 6, lane = threadIdx.x & 63;
  const int row = blockIdx.x*4 + wave;
  const f32x4* hp = (const f32x4*)(hbuf + (size_t)row*DMODEL);
  const f32x4* xp = (const f32x4*)(x    + (size_t)row*DMODEL);
  f32x4 y = hp[lane] + xp[lane];
  float s = y[0] + y[1] + y[2] + y[3];
  s += __shfl_xor(s, 1);  s += __shfl_xor(s, 2);  s += __shfl_xor(s, 4);
  s += __shfl_xor(s, 8);  s += __shfl_xor(s, 16); s += __shfl_xor(s, 32);
  float mu = s * (1.0f/256.0f);
  f32x4 d = y - mu;
  float vs = d[0]*d[0] + d[1]*d[1] + d[2]*d[2] + d[3]*d[3];
  vs += __shfl_xor(vs, 1);  vs += __shfl_xor(vs, 2);  vs += __shfl_xor(vs, 4);
  vs += __shfl_xor(vs, 8);  vs += __shfl_xor(vs, 16); vs += __shfl_xor(vs, 32);
  float rs = rsqrtf(vs * (1.0f/256.0f) + 1e-5f);
  f32x4 g = ((const f32x4*)gamma)[lane];
  f32x4 b = ((const f32x4*)beta)[lane];
  f32x4 o = d*rs*g + b;
  ((f32x4*)(out + (size_t)row*DMODEL))[lane] = o;
}

// ---------------- launch ----------------
extern "C" void kernel_launch(void* const* d_in, const int* in_sizes, int n_in,
                              void* d_out, int out_size, void* d_ws, size_t ws_size,
                              hipStream_t stream){
  const float* x     = (const float*)d_in[0];
  const float* adj   = (const float*)d_in[1];
  const float* Wq    = (const float*)d_in[2];
  const float* bq    = (const float*)d_in[3];
  const float* Wk    = (const float*)d_in[4];
  const float* bk    = (const float*)d_in[5];
  const float* Wv    = (const float*)d_in[6];
  const float* bv    = (const float*)d_in[7];
  const float* gamma = (const float*)d_in[8];
  const float* beta  = (const float*)d_in[9];
  float* out = (float*)d_out;
  char* ws = (char*)d_ws;

  // workspace carve (bytes)
  u16*   xb   = (u16*)  (ws + 0);            // 38400*256*2   = 19,660,800
  u16*   wqkv = (u16*)  (ws + 19660800);     // 768*256*2     = 393,216
  float* bqkv = (float*)(ws + 20054016);     // 768*4         = 3,072
  u16*   qkv  = (u16*)  (ws + 20057088);     // 38400*768*2   = 58,982,400
  float* hbuf = (float*)(ws + 79039488);     // 38400*256*4   = 39,321,600  -> ends 118,361,088

  cast_x_kernel<<<4800, 256, 0, stream>>>(x, xb, 9830400/8);
  prep_w_kernel<<<192, 256, 0, stream>>>(Wq, Wk, Wv, bq, bk, bv, wqkv, bqkv);
  gemm_qkv_kernel<<<1800, 256, 0, stream>>>(xb, wqkv, bqkv, qkv);
  (void)hipFuncSetAttribute((const void*)attn_kernel,
                            hipFuncAttributeMaxDynamicSharedMemorySize, ATTN_LDS);
  attn_kernel<<<768, 512, ATTN_LDS, stream>>>(qkv, adj, hbuf);
  resid_ln_kernel<<<9600, 256, 0, stream>>>(hbuf, x, gamma, beta, out);
}

// Round 7
// 254.233 us; speedup vs baseline: 1.6463x; 1.0143x over previous
//
#include <hip/hip_runtime.h>
#include <cstdint>
#include <cstddef>

typedef unsigned short u16;
typedef __attribute__((ext_vector_type(8))) __bf16 bf16x8;
typedef __attribute__((ext_vector_type(4))) float f32x4;
typedef __attribute__((ext_vector_type(8))) u16 u16x8;
typedef __attribute__((ext_vector_type(4))) u16 u16x4;

#define MTOT   38400   // B*T*N rows
#define DMODEL 256
#define NQKV   768
#define NN     400
#define NBT    96      // B*T
#define SCALE  0.17677669529663687f   // 1/sqrt(32), folded into Wq/bq at prep

__device__ __forceinline__ u16 f2b(float f){
  __bf16 b = (__bf16)f;
  return __builtin_bit_cast(u16, b);
}

__device__ __forceinline__ void g2l16(const void* g, void* l){
  __builtin_amdgcn_global_load_lds(
      (const __attribute__((address_space(1))) unsigned int*)g,
      (__attribute__((address_space(3))) unsigned int*)l,
      16, 0, 0);
}

// ---------------- prep: cast x -> bf16 ----------------
__global__ __launch_bounds__(256) void cast_x_kernel(const float* __restrict__ x,
                                                     u16* __restrict__ xb, int n8){
  int i = blockIdx.x * 256 + threadIdx.x;
  if (i >= n8) return;
  const f32x4* xp = (const f32x4*)x;
  f32x4 a = xp[2*i], b = xp[2*i+1];
  u16x8 o;
  o[0]=f2b(a[0]); o[1]=f2b(a[1]); o[2]=f2b(a[2]); o[3]=f2b(a[3]);
  o[4]=f2b(b[0]); o[5]=f2b(b[1]); o[6]=f2b(b[2]); o[7]=f2b(b[3]);
  ((u16x8*)xb)[i] = o;
}

// ---------------- prep: pack Wq*S/Wk/Wv -> bf16 [768][256], bias -> f32[768] ----------------
__global__ __launch_bounds__(256) void prep_w_kernel(
    const float* __restrict__ wq, const float* __restrict__ wk, const float* __restrict__ wv,
    const float* __restrict__ bq, const float* __restrict__ bk, const float* __restrict__ bv,
    u16* __restrict__ wqkv, float* __restrict__ bqkv){
  int i = blockIdx.x * 256 + threadIdx.x;      // 49152 threads, 4 elems each
  int g = i >> 14;                              // 16384 float4 per matrix
  int rem = (i & 16383) * 4;
  const float* w = (g == 0) ? wq : ((g == 1) ? wk : wv);
  float sc = (g == 0) ? SCALE : 1.0f;           // fold 1/sqrt(hd) into Q projection
  f32x4 v = *(const f32x4*)(w + rem);
  u16x4 o; o[0]=f2b(v[0]*sc); o[1]=f2b(v[1]*sc); o[2]=f2b(v[2]*sc); o[3]=f2b(v[3]*sc);
  *(u16x4*)(wqkv + (size_t)i*4) = o;
  if (i < NQKV) bqkv[i] = (i < 256) ? bq[i]*SCALE : ((i < 512) ? bk[i-256] : bv[i-512]);
}

// ---------------- QKV GEMM, 2-phase pipelined (counted vmcnt) ----------------
__global__ __launch_bounds__(256,2) void gemm_qkv_kernel(
    const u16* __restrict__ xb, const u16* __restrict__ wqkv,
    const float* __restrict__ bqkv, u16* __restrict__ qkv){
  __shared__ u16 a_lds[2][128*64];
  __shared__ u16 b_lds[2][128*64];
  const int tid = threadIdx.x, lane = tid & 63, wave = tid >> 6;
  const int bn = blockIdx.x % 6, bm = blockIdx.x / 6;
  const int m0 = bm*128, n0 = bn*128;
  const int wm = (wave>>1)*64, wn = (wave&1)*64;
  const int lr = lane & 15, lk = lane >> 4;
  f32x4 acc[4][4] = {};

  auto stage = [&](int buf, int k0){
    #pragma unroll
    for (int i = 0; i < 4; ++i){
      int off  = (wave*4 + i)*1024 + lane*16;   // byte offset in 16KB tile
      int row  = off >> 7;                      // /128B per row (64 bf16)
      int colb = off & 127;
      int scolb = colb ^ ((row & 7) << 4);      // inverse-swizzled SOURCE (rule #21)
      g2l16(xb   + (size_t)(m0+row)*256 + k0 + (scolb>>1), (char*)a_lds[buf] + (wave*4+i)*1024);
      g2l16(wqkv + (size_t)(n0+row)*256 + k0 + (scolb>>1), (char*)b_lds[buf] + (wave*4+i)*1024);
    }
  };

  stage(0, 0);
  #pragma unroll
  for (int ks = 0; ks < 4; ++ks){
    if (ks < 3){
      stage((ks+1)&1, (ks+1)*64);
      asm volatile("s_waitcnt vmcnt(8)" ::: "memory");   // own prev-step loads done; next 8 in flight
    } else {
      asm volatile("s_waitcnt vmcnt(0)" ::: "memory");
    }
    __builtin_amdgcn_s_barrier();
    const char* al = (const char*)a_lds[ks&1];
    const char* bl = (const char*)b_lds[ks&1];
    #pragma unroll
    for (int sub = 0; sub < 2; ++sub){
      bf16x8 af[4], bfr[4];
      #pragma unroll
      for (int i = 0; i < 4; ++i){
        int ra = wm + i*16 + lr;
        af[i]  = *(const bf16x8*)(al + ra*128 + ((sub*64 + lk*16) ^ ((ra&7)<<4)));
        int rb = wn + i*16 + lr;
        bfr[i] = *(const bf16x8*)(bl + rb*128 + ((sub*64 + lk*16) ^ ((rb&7)<<4)));
      }
      #pragma unroll
      for (int i = 0; i < 4; ++i)
        #pragma unroll
        for (int j = 0; j < 4; ++j)
          acc[i][j] = __builtin_amdgcn_mfma_f32_16x16x32_bf16(af[i], bfr[j], acc[i][j], 0, 0, 0);
    }
    __builtin_amdgcn_s_barrier();
  }
  #pragma unroll
  for (int j = 0; j < 4; ++j){
    int n = n0 + wn + j*16 + lr;               // D col = lane&15
    float bias = bqkv[n];
    #pragma unroll
    for (int i = 0; i < 4; ++i){
      int mb = m0 + wm + i*16 + lk*4;          // D row = (lane>>4)*4 + r
      #pragma unroll
      for (int r = 0; r < 4; ++r)
        qkv[(size_t)(mb + r)*NQKV + n] = f2b(acc[i][j][r] + bias);
    }
  }
}

// ---------------- attention: per (b,t,h) block, 8 waves, flash online softmax, P-in-registers ----------------
// PV trick: QK^T output at lane (lq,lk) is P[q=lq][k=4lk+r] == x32 A-frag positions e=0..3
// (k'=8lk+e) if e=4..7 are zeroed; B (vT) is read at the matching addresses, its e=4..7
// garbage is annihilated by the zero half. No P shuffle, no P LDS.
// LDS: K  [400][32] bf16 XOR-swizzled, 25600 B
//      vT [32][428] bf16, stride 856B (214 dwords = 22 mod 32 -> 16 row bank phases), 27392 B
// total 52992 B -> 3 blocks/CU = 24 waves/CU; grid 768 = 3*256 -> zero tail.
#define K_BYTES   25600
#define VT_BYTES  (32*856)
#define ATTN_LDS  (K_BYTES + VT_BYTES)   // 52992

__global__ __launch_bounds__(512,4) void attn_kernel(
    const u16* __restrict__ qkv, const float* __restrict__ adj, float* __restrict__ hout){
  extern __shared__ __align__(16) char smem[];
  char* vT = smem + K_BYTES;
  const int tid = threadIdx.x, lane = tid & 63, wave = tid >> 6;
  const int h = blockIdx.x / NBT, bt = blockIdx.x % NBT;   // bid%8 == bt%8 -> same-bt heads share an XCD
  const int lq = lane & 15, lk = lane >> 4;
  const u16* qkvbt = qkv + (size_t)bt*NN*NQKV + h*32;

  // ---- stage K [400][32] via global_load_lds (16B), pre-swizzled source, linear LDS dest
  {
    const u16* kbase = qkvbt + 256;
    int rsub = lane >> 2;                 // 0..15
    int colb = (lane & 3) * 16;           // 0,16,32,48 bytes
    for (int c = wave; c < 25; c += 8){
      int row  = c*16 + rsub;
      int scol = colb ^ ((row & 3) << 4); // inverse swizzle on SOURCE
      g2l16(kbase + (size_t)row*NQKV + (scol >> 1), smem + c*1024);
    }
  }
  // ---- stage V transposed: value (d,k) at byte d*856 + k*2 (no swizzle; stride dephases rows)
  for (int c = tid; c < 1600; c += 512){
    int row = c >> 2, cc = (c & 3)*8;     // row = k index, cc = d base
    u16x8 v = *(const u16x8*)(qkvbt + 512 + (size_t)row*NQKV + cc);
    #pragma unroll
    for (int e = 0; e < 8; ++e)
      *(u16*)(vT + (cc+e)*856 + row*2) = v[e];
  }
  __syncthreads();

  const float* adjbt = adj + (size_t)bt*NN*NN;
  const f32x4 z = {0.f, 0.f, 0.f, 0.f};

  for (int t25 = wave; t25 < 25; t25 += 8){
    const int q0 = t25*16;
    // Q B-frag from global: B[row=lane&15 = q][k=(lane>>4)*8+e]
    bf16x8 qf = *(const bf16x8*)(qkvbt + (size_t)(q0 + lq)*NQKV + lk*8);
    const float* arow = adjbt + (size_t)(q0 + lq)*NN;
    const char* v0base = vT + lq*856;
    const char* v1base = vT + (16+lq)*856;
    f32x4 o0 = z, o1 = z;
    float m_run = -1e30f, l_run = 0.f;
    // adj prefetch for window 0
    f32x4 a0 = *(const f32x4*)(arow + lk*4);
    f32x4 a1 = *(const f32x4*)(arow + 16 + lk*4);

    #pragma unroll
    for (int w = 0; w < 12; ++w){
      // QK^T (swapped): lane holds S[q=lq][k = w*32 + lk*4+r (+16)]
      int r0 = w*32 + lq;
      int r1 = w*32 + 16 + lq;
      bf16x8 k0 = *(const bf16x8*)((const char*)smem + r0*64 + ((lk*16) ^ ((r0 & 3) << 4)));
      bf16x8 k1 = *(const bf16x8*)((const char*)smem + r1*64 + ((lk*16) ^ ((r1 & 3) << 4)));
      __builtin_amdgcn_s_setprio(1);
      f32x4 s0 = __builtin_amdgcn_mfma_f32_16x16x32_bf16(k0, qf, z, 0, 0, 0);
      f32x4 s1 = __builtin_amdgcn_mfma_f32_16x16x32_bf16(k1, qf, z, 0, 0, 0);
      __builtin_amdgcn_s_setprio(0);
      f32x4 ca0 = a0, ca1 = a1;
      if (w < 11){
        a0 = *(const f32x4*)(arow + (w+1)*32 + lk*4);
        a1 = *(const f32x4*)(arow + (w+1)*32 + 16 + lk*4);
      } else {
        a0 = *(const f32x4*)(arow + 384 + lk*4);   // tail window adj
      }
      s0 *= ca0; s1 *= ca1;
      // window max for row lq
      float wmx = fmaxf(fmaxf(fmaxf(s0[0],s0[1]), fmaxf(s0[2],s0[3])),
                        fmaxf(fmaxf(s1[0],s1[1]), fmaxf(s1[2],s1[3])));
      wmx = fmaxf(wmx, __shfl_xor(wmx, 16)); wmx = fmaxf(wmx, __shfl_xor(wmx, 32));
      // deferred-max update (T13): rescale only when some row grows past THR=8
      if (!__all(wmx <= m_run + 8.f)){
        float m_new = fmaxf(m_run, wmx);
        float sc = __expf(m_run - m_new);
        m_run = m_new;
        l_run *= sc;
        float osc0 = __shfl(sc, lk*4+0), osc1 = __shfl(sc, lk*4+1);
        float osc2 = __shfl(sc, lk*4+2), osc3 = __shfl(sc, lk*4+3);
        o0[0]*=osc0; o0[1]*=osc1; o0[2]*=osc2; o0[3]*=osc3;
        o1[0]*=osc0; o1[1]*=osc1; o1[2]*=osc2; o1[3]*=osc3;
      }
      // exp + pack P into x32 A-frags (low half real, high half zero)
      u16x8 A0 = {0,0,0,0,0,0,0,0}, A1 = {0,0,0,0,0,0,0,0};
      float ls = 0.f;
      #pragma unroll
      for (int j = 0; j < 4; ++j){
        float t0 = __expf(s0[j] - m_run);
        float t1 = __expf(s1[j] - m_run);
        A0[j] = f2b(t0); A1[j] = f2b(t1);
        ls += t0 + t1;
      }
      l_run += ls;
      // vT B-frags: e=0..3 at real k = w*32 (+16) + 4lk + 0..3; e=4..7 garbage (times zero)
      u16x4 lo00 = *(const u16x4*)(v0base + w*64      + lk*8);
      u16x4 lo01 = *(const u16x4*)(v0base + w*64 + 32 + lk*8);
      u16x4 lo10 = *(const u16x4*)(v1base + w*64      + lk*8);
      u16x4 lo11 = *(const u16x4*)(v1base + w*64 + 32 + lk*8);
      u16x8 vb00 = {lo00[0],lo00[1],lo00[2],lo00[3], lo00[0],lo00[1],lo00[2],lo00[3]};
      u16x8 vb01 = {lo01[0],lo01[1],lo01[2],lo01[3], lo01[0],lo01[1],lo01[2],lo01[3]};
      u16x8 vb10 = {lo10[0],lo10[1],lo10[2],lo10[3], lo10[0],lo10[1],lo10[2],lo10[3]};
      u16x8 vb11 = {lo11[0],lo11[1],lo11[2],lo11[3], lo11[0],lo11[1],lo11[2],lo11[3]};
      o0 = __builtin_amdgcn_mfma_f32_16x16x32_bf16(__builtin_bit_cast(bf16x8, A0),
                                                   __builtin_bit_cast(bf16x8, vb00), o0, 0, 0, 0);
      o1 = __builtin_amdgcn_mfma_f32_16x16x32_bf16(__builtin_bit_cast(bf16x8, A0),
                                                   __builtin_bit_cast(bf16x8, vb10), o1, 0, 0, 0);
      o0 = __builtin_amdgcn_mfma_f32_16x16x32_bf16(__builtin_bit_cast(bf16x8, A1),
                                                   __builtin_bit_cast(bf16x8, vb01), o0, 0, 0, 0);
      o1 = __builtin_amdgcn_mfma_f32_16x16x32_bf16(__builtin_bit_cast(bf16x8, A1),
                                                   __builtin_bit_cast(bf16x8, vb11), o1, 0, 0, 0);
    }
    // ---- tail window: k 384..399 only
    {
      int r0 = 384 + lq;
      bf16x8 k0 = *(const bf16x8*)((const char*)smem + r0*64 + ((lk*16) ^ ((r0 & 3) << 4)));
      f32x4 s0 = __builtin_amdgcn_mfma_f32_16x16x32_bf16(k0, qf, z, 0, 0, 0);
      s0 *= a0;                                  // a0 = arow[384 + lk*4..] from prefetch
      float wmx = fmaxf(fmaxf(s0[0],s0[1]), fmaxf(s0[2],s0[3]));
      wmx = fmaxf(wmx, __shfl_xor(wmx, 16)); wmx = fmaxf(wmx, __shfl_xor(wmx, 32));
      if (!__all(wmx <= m_run + 8.f)){
        float m_new = fmaxf(m_run, wmx);
        float sc = __expf(m_run - m_new);
        m_run = m_new;
        l_run *= sc;
        float osc0 = __shfl(sc, lk*4+0), osc1 = __shfl(sc, lk*4+1);
        float osc2 = __shfl(sc, lk*4+2), osc3 = __shfl(sc, lk*4+3);
        o0[0]*=osc0; o0[1]*=osc1; o0[2]*=osc2; o0[3]*=osc3;
        o1[0]*=osc0; o1[1]*=osc1; o1[2]*=osc2; o1[3]*=osc3;
      }
      u16x8 A0 = {0,0,0,0,0,0,0,0};
      float ls = 0.f;
      #pragma unroll
      for (int j = 0; j < 4; ++j){
        float t0 = __expf(s0[j] - m_run);
        A0[j] = f2b(t0);
        ls += t0;
      }
      l_run += ls;
      u16x4 lo00 = *(const u16x4*)(v0base + 12*64 + lk*8);
      u16x4 lo10 = *(const u16x4*)(v1base + 12*64 + lk*8);
      u16x8 vb00 = {lo00[0],lo00[1],lo00[2],lo00[3], lo00[0],lo00[1],lo00[2],lo00[3]};
      u16x8 vb10 = {lo10[0],lo10[1],lo10[2],lo10[3], lo10[0],lo10[1],lo10[2],lo10[3]};
      o0 = __builtin_amdgcn_mfma_f32_16x16x32_bf16(__builtin_bit_cast(bf16x8, A0),
                                                   __builtin_bit_cast(bf16x8, vb00), o0, 0, 0, 0);
      o1 = __builtin_amdgcn_mfma_f32_16x16x32_bf16(__builtin_bit_cast(bf16x8, A0),
                                                   __builtin_bit_cast(bf16x8, vb10), o1, 0, 0, 0);
    }
    // ---- final row-sum reduce + epilogue
    float l = l_run;
    l += __shfl_xor(l, 16); l += __shfl_xor(l, 32);
    float inv = 1.0f / l;
    float* orow = hout + (size_t)(bt*NN + q0)*DMODEL + h*32;
    #pragma unroll
    for (int r = 0; r < 4; ++r){
      float invq = __shfl(inv, lk*4 + r);
      orow[(lk*4 + r)*DMODEL + lq]      = o0[r]*invq;
      orow[(lk*4 + r)*DMODEL + 16 + lq] = o1[r]*invq;
    }
  }
}

// ---------------- residual + LayerNorm ----------------
__global__ __launch_bounds__(256) void resid_ln_kernel(
    const float* __restrict__ hbuf, const float* __restrict__ x,
    const float* __restrict__ gamma, const float* __restrict__ beta,
    float* __restrict__ out){
  const int wave = threadIdx.x >> 6, lane = threadIdx.x & 63;
  const int row = blockIdx.x*4 + wave;
  const f32x4* hp = (const f32x4*)(hbuf + (size_t)row*DMODEL);
  const f32x4* xp = (const f32x4*)(x    + (size_t)row*DMODEL);
  f32x4 y = hp[lane] + xp[lane];
  float s = y[0] + y[1] + y[2] + y[3];
  s += __shfl_xor(s, 1);  s += __shfl_xor(s, 2);  s += __shfl_xor(s, 4);
  s += __shfl_xor(s, 8);  s += __shfl_xor(s, 16); s += __shfl_xor(s, 32);
  float mu = s * (1.0f/256.0f);
  f32x4 d = y - mu;
  float vs = d[0]*d[0] + d[1]*d[1] + d[2]*d[2] + d[3]*d[3];
  vs += __shfl_xor(vs, 1);  vs += __shfl_xor(vs, 2);  vs += __shfl_xor(vs, 4);
  vs += __shfl_xor(vs, 8);  vs += __shfl_xor(vs, 16); vs += __shfl_xor(vs, 32);
  float rs = rsqrtf(vs * (1.0f/256.0f) + 1e-5f);
  f32x4 g = ((const f32x4*)gamma)[lane];
  f32x4 b = ((const f32x4*)beta)[lane];
  f32x4 o = d*rs*g + b;
  ((f32x4*)(out + (size_t)row*DMODEL))[lane] = o;
}

// ---------------- launch ----------------
extern "C" void kernel_launch(void* const* d_in, const int* in_sizes, int n_in,
                              void* d_out, int out_size, void* d_ws, size_t ws_size,
                              hipStream_t stream){
  const float* x     = (const float*)d_in[0];
  const float* adj   = (const float*)d_in[1];
  const float* Wq    = (const float*)d_in[2];
  const float* bq    = (const float*)d_in[3];
  const float* Wk    = (const float*)d_in[4];
  const float* bk    = (const float*)d_in[5];
  const float* Wv    = (const float*)d_in[6];
  const float* bv    = (const float*)d_in[7];
  const float* gamma = (const float*)d_in[8];
  const float* beta  = (const float*)d_in[9];
  float* out = (float*)d_out;
  char* ws = (char*)d_ws;

  // workspace carve (bytes)
  u16*   xb   = (u16*)  (ws + 0);            // 38400*256*2   = 19,660,800
  u16*   wqkv = (u16*)  (ws + 19660800);     // 768*256*2     = 393,216
  float* bqkv = (float*)(ws + 20054016);     // 768*4         = 3,072
  u16*   qkv  = (u16*)  (ws + 20057088);     // 38400*768*2   = 58,982,400
  float* hbuf = (float*)(ws + 79039488);     // 38400*256*4   = 39,321,600  -> ends 118,361,088

  cast_x_kernel<<<4800, 256, 0, stream>>>(x, xb, 9830400/8);
  prep_w_kernel<<<192, 256, 0, stream>>>(Wq, Wk, Wv, bq, bk, bv, wqkv, bqkv);
  gemm_qkv_kernel<<<1800, 256, 0, stream>>>(xb, wqkv, bqkv, qkv);
  (void)hipFuncSetAttribute((const void*)attn_kernel,
                            hipFuncAttributeMaxDynamicSharedMemorySize, ATTN_LDS);
  attn_kernel<<<768, 512, ATTN_LDS, stream>>>(qkv, adj, hbuf);
  resid_ln_kernel<<<9600, 256, 0, stream>>>(hbuf, x, gamma, beta, out);
}